// Round 1
// baseline (1027.777 us; speedup 1.0000x reference)
//
#include <hip/hip_runtime.h>
#include <cstdint>
#include <cstddef>

// Problem constants (match reference)
#define BTOT    4096
#define SRCLEN  128
#define INDIM   16
#define HDIM    64
#define SEQLEN  100
#define MEANS_N (BTOT * SEQLEN * 4)   // 1638400

// ---------- helpers ----------
__device__ __forceinline__ float dot4(float4 a, float4 b) {
    return fmaf(a.x, b.x, fmaf(a.y, b.y, fmaf(a.z, b.z, a.w * b.w)));
}

// quad butterfly reduce across lanes {4k,4k+1,4k+2,4k+3}; all 4 lanes end with the sum.
template <int CTRL>
__device__ __forceinline__ float dpp_xadd(float v) {
    float o = __int_as_float(__builtin_amdgcn_mov_dpp(__float_as_int(v), CTRL, 0xF, 0xF, true));
    return v + o;
}
__device__ __forceinline__ float quad_sum(float v) {
    v = dpp_xadd<0xB1>(v);  // quad_perm(1,0,3,2)  xor 1
    v = dpp_xadd<0x4E>(v);  // quad_perm(2,3,0,1)  xor 2
    return v;
}

__device__ __forceinline__ float sigmoidf_(float x) { return 1.0f / (1.0f + __expf(-x)); }
__device__ __forceinline__ float tanhf_(float x) {
    float e = __expf(2.0f * x);
    return 1.0f - 2.0f / (e + 1.0f);
}
__device__ __forceinline__ float gelu_exact(float x) {
    return 0.5f * x * (1.0f + erff(x * 0.70710678118654752440f));
}

// =====================================================================
// Encoder GRU: 128 steps.  WG=256 threads = 64 units x 4 k-quads, batch tile 4.
// Weights register-resident per thread; h in LDS; quad-DPP split-K reduce.
// =====================================================================
__global__ __launch_bounds__(256, 4) void enc_kernel(
    const float* __restrict__ x,
    const float* __restrict__ Wih, const float* __restrict__ bih,
    const float* __restrict__ Whh, const float* __restrict__ bhh,
    float* __restrict__ enc_h)
{
    const int tid = threadIdx.x;
    const int kq  = tid & 3;        // k-quad 0..3
    const int u   = tid >> 2;       // unit 0..63
    const int b0  = blockIdx.x * 4; // batch tile base

    __shared__ __align__(16) float h_lds[4][HDIM];
    { int bb = tid >> 6, uu = tid & 63; h_lds[bb][uu] = 0.0f; }

    // Register-resident weight fragments: rows u, u+64, u+128; h-slice [16kq,16kq+16), x-slice [4kq,4kq+4)
    float4 wr[4], wz[4], wn[4];
    #pragma unroll
    for (int c = 0; c < 4; ++c) {
        wr[c] = *(const float4*)(Whh + (size_t)(u)        * HDIM + 16 * kq + 4 * c);
        wz[c] = *(const float4*)(Whh + (size_t)(u + 64)   * HDIM + 16 * kq + 4 * c);
        wn[c] = *(const float4*)(Whh + (size_t)(u + 128)  * HDIM + 16 * kq + 4 * c);
    }
    const float4 xr = *(const float4*)(Wih + (size_t)(u)       * INDIM + 4 * kq);
    const float4 xz = *(const float4*)(Wih + (size_t)(u + 64)  * INDIM + 4 * kq);
    const float4 xn = *(const float4*)(Wih + (size_t)(u + 128) * INDIM + 4 * kq);
    const float br   = bih[u]       + bhh[u];
    const float bz   = bih[u + 64]  + bhh[u + 64];
    const float bin_ = bih[u + 128];               // n-gate: keep x-part and h-part separate
    const float bhn  = bhh[u + 128];

    __syncthreads();

    for (int t = 0; t < SRCLEN; ++t) {
        float ar[4], az[4], anh[4], anx[4], hold[4];
        #pragma unroll
        for (int b = 0; b < 4; ++b) {
            const float4* hp = (const float4*)(&h_lds[b][16 * kq]);
            const float4 h0 = hp[0], h1 = hp[1], h2 = hp[2], h3 = hp[3];
            const float4 xv = *(const float4*)(x + ((size_t)(b0 + b) * SRCLEN + t) * INDIM + 4 * kq);
            float r_  = dot4(wr[0], h0) + dot4(wr[1], h1) + dot4(wr[2], h2) + dot4(wr[3], h3) + dot4(xr, xv);
            float z_  = dot4(wz[0], h0) + dot4(wz[1], h1) + dot4(wz[2], h2) + dot4(wz[3], h3) + dot4(xz, xv);
            float nh_ = dot4(wn[0], h0) + dot4(wn[1], h1) + dot4(wn[2], h2) + dot4(wn[3], h3);
            float nx_ = dot4(xn, xv);
            ar[b]  = quad_sum(r_);
            az[b]  = quad_sum(z_);
            anh[b] = quad_sum(nh_);
            anx[b] = quad_sum(nx_);
            hold[b] = h_lds[b][u];
        }
        __syncthreads();
        #pragma unroll
        for (int b = 0; b < 4; ++b) {
            float r = sigmoidf_(ar[b] + br);
            float z = sigmoidf_(az[b] + bz);
            float n = tanhf_(anx[b] + bin_ + r * (anh[b] + bhn));
            float hnew = (1.0f - z) * n + z * hold[b];
            if (kq == 0) h_lds[b][u] = hnew;   // all quad lanes have identical value; one writes
        }
        __syncthreads();
    }

    { int bb = tid >> 6, uu = tid & 63;
      enc_h[(size_t)(b0 + bb) * HDIM + uu] = h_lds[bb][uu]; }
}

// =====================================================================
// Decoder GRU: 100 autoregressive steps.  Same tiling as encoder plus:
//   phase3: out-projection o = h @ outW^T + outb (wave w handles batch w),
//   o fed back through LDS into next step's gi, and streamed to global dec_o.
// =====================================================================
__global__ __launch_bounds__(256, 3) void dec_kernel(
    const float* __restrict__ trg,
    const float* __restrict__ Wih, const float* __restrict__ bih,
    const float* __restrict__ Whh, const float* __restrict__ bhh,
    const float* __restrict__ outW, const float* __restrict__ outb,
    const float* __restrict__ embW, const float* __restrict__ embb,
    const float* __restrict__ enc_h,
    float* __restrict__ dec_o)
{
    const int tid = threadIdx.x;
    const int kq  = tid & 3;
    const int u   = tid >> 2;      // 0..63
    const int w   = tid >> 6;      // wave id 0..3 (handles batch b=w in phase3)
    const int ul  = u & 15;        // out-projection row 0..15
    const int b0  = blockIdx.x * 4;

    __shared__ __align__(16) float h_lds[4][HDIM];
    __shared__ __align__(16) float o_lds[4][INDIM];

    { int bb = tid >> 6, uu = tid & 63;
      h_lds[bb][uu] = enc_h[(size_t)(b0 + bb) * HDIM + uu]; }
    if (tid < 64) {  // init_in = trg @ embW^T + embb
        int bb = tid >> 4, ii = tid & 15;
        float s = embb[ii];
        #pragma unroll
        for (int q = 0; q < 4; ++q)
            s = fmaf(embW[ii * 4 + q], trg[(size_t)(b0 + bb) * 4 + q], s);
        o_lds[bb][ii] = s;
    }

    float4 wr[4], wz[4], wn[4];
    #pragma unroll
    for (int c = 0; c < 4; ++c) {
        wr[c] = *(const float4*)(Whh + (size_t)(u)        * HDIM + 16 * kq + 4 * c);
        wz[c] = *(const float4*)(Whh + (size_t)(u + 64)   * HDIM + 16 * kq + 4 * c);
        wn[c] = *(const float4*)(Whh + (size_t)(u + 128)  * HDIM + 16 * kq + 4 * c);
    }
    const float4 gr = *(const float4*)(Wih + (size_t)(u)       * INDIM + 4 * kq);
    const float4 gz = *(const float4*)(Wih + (size_t)(u + 64)  * INDIM + 4 * kq);
    const float4 gn = *(const float4*)(Wih + (size_t)(u + 128) * INDIM + 4 * kq);
    const float br   = bih[u]       + bhh[u];
    const float bz   = bih[u + 64]  + bhh[u + 64];
    const float bin_ = bih[u + 128];
    const float bhn  = bhh[u + 128];
    float4 ow[4];
    #pragma unroll
    for (int c = 0; c < 4; ++c)
        ow[c] = *(const float4*)(outW + (size_t)ul * HDIM + 16 * kq + 4 * c);
    const float ob = outb[ul];

    __syncthreads();

    for (int t = 0; t < SEQLEN; ++t) {
        // phase1: gate dot products (reads h_lds old, o_lds old)
        float ar[4], az[4], anh[4], anx[4], hold[4];
        #pragma unroll
        for (int b = 0; b < 4; ++b) {
            const float4* hp = (const float4*)(&h_lds[b][16 * kq]);
            const float4 h0 = hp[0], h1 = hp[1], h2 = hp[2], h3 = hp[3];
            const float4 ov = *(const float4*)(&o_lds[b][4 * kq]);
            float r_  = dot4(wr[0], h0) + dot4(wr[1], h1) + dot4(wr[2], h2) + dot4(wr[3], h3) + dot4(gr, ov);
            float z_  = dot4(wz[0], h0) + dot4(wz[1], h1) + dot4(wz[2], h2) + dot4(wz[3], h3) + dot4(gz, ov);
            float nh_ = dot4(wn[0], h0) + dot4(wn[1], h1) + dot4(wn[2], h2) + dot4(wn[3], h3);
            float nx_ = dot4(gn, ov);
            ar[b]  = quad_sum(r_);
            az[b]  = quad_sum(z_);
            anh[b] = quad_sum(nh_);
            anx[b] = quad_sum(nx_);
            hold[b] = h_lds[b][u];
        }
        __syncthreads();
        // phase2: pointwise GRU update, write h_new
        #pragma unroll
        for (int b = 0; b < 4; ++b) {
            float r = sigmoidf_(ar[b] + br);
            float z = sigmoidf_(az[b] + bz);
            float n = tanhf_(anx[b] + bin_ + r * (anh[b] + bhn));
            float hnew = (1.0f - z) * n + z * hold[b];
            if (kq == 0) h_lds[b][u] = hnew;
        }
        __syncthreads();
        // phase3: o = h_new @ outW^T + outb ; wave w computes batch b=w
        {
            const float4* hp = (const float4*)(&h_lds[w][16 * kq]);
            float acc = dot4(ow[0], hp[0]) + dot4(ow[1], hp[1]) + dot4(ow[2], hp[2]) + dot4(ow[3], hp[3]);
            acc = quad_sum(acc) + ob;
            if (kq == 0) {
                o_lds[w][ul] = acc;
                dec_o[(((size_t)(b0 + w) * SEQLEN) + t) * INDIM + ul] = acc;
            }
        }
        __syncthreads();
    }
}

// =====================================================================
// Heads: 409600 independent rows; one thread per row.
// Weight rows are wave-uniform -> compiler emits s_load; fma takes SGPR operand.
// =====================================================================
__global__ void heads_kernel(
    const float* __restrict__ dec_o,
    const float* __restrict__ mW1, const float* __restrict__ mb1,
    const float* __restrict__ mW2, const float* __restrict__ mb2,
    const float* __restrict__ cW1, const float* __restrict__ cb1,
    const float* __restrict__ cW2, const float* __restrict__ cb2,
    float* __restrict__ out)
{
    const size_t r = (size_t)blockIdx.x * 256 + threadIdx.x;  // 0..409599

    float o16[16];
    {
        const float4* op = (const float4*)(dec_o + r * 16);
        #pragma unroll
        for (int c = 0; c < 4; ++c) {
            float4 v = op[c];
            o16[4 * c + 0] = v.x; o16[4 * c + 1] = v.y;
            o16[4 * c + 2] = v.z; o16[4 * c + 3] = v.w;
        }
    }

    float m[4], cv[10];
    #pragma unroll
    for (int j = 0; j < 4; ++j)  m[j]  = mb2[j];
    #pragma unroll
    for (int j = 0; j < 10; ++j) cv[j] = cb2[j];

    #pragma unroll 8
    for (int hu = 0; hu < 64; ++hu) {
        const float* w1m = mW1 + hu * 16;
        float hm = mb1[hu];
        #pragma unroll
        for (int i = 0; i < 16; ++i) hm = fmaf(w1m[i], o16[i], hm);
        float gm = gelu_exact(hm);
        #pragma unroll
        for (int j = 0; j < 4; ++j) m[j] = fmaf(mW2[j * 64 + hu], gm, m[j]);

        const float* w1c = cW1 + hu * 16;
        float hc = cb1[hu];
        #pragma unroll
        for (int i = 0; i < 16; ++i) hc = fmaf(w1c[i], o16[i], hc);
        float gc = gelu_exact(hc);
        #pragma unroll
        for (int j = 0; j < 10; ++j) cv[j] = fmaf(cW2[j * 64 + hu], gc, cv[j]);
    }

    // clamp means[2],[3] to [-1,1]; [0],[1] pass through
    m[2] = fminf(fmaxf(m[2], -1.0f), 1.0f);
    m[3] = fminf(fmaxf(m[3], -1.0f), 1.0f);

    float* means = out;
    float* covs  = out + MEANS_N;
    #pragma unroll
    for (int j = 0; j < 4; ++j)  means[r * 4 + j]  = m[j];
    #pragma unroll
    for (int j = 0; j < 10; ++j) covs[r * 10 + j]  = cv[j];
}

// =====================================================================
extern "C" void kernel_launch(void* const* d_in, const int* in_sizes, int n_in,
                              void* d_out, int out_size, void* d_ws, size_t ws_size,
                              hipStream_t stream)
{
    const float* x    = (const float*)d_in[0];
    const float* trg  = (const float*)d_in[1];
    const float* eWih = (const float*)d_in[2];
    const float* ebih = (const float*)d_in[3];
    const float* eWhh = (const float*)d_in[4];
    const float* ebhh = (const float*)d_in[5];
    const float* dWih = (const float*)d_in[6];
    const float* dbih = (const float*)d_in[7];
    const float* dWhh = (const float*)d_in[8];
    const float* dbhh = (const float*)d_in[9];
    const float* outW = (const float*)d_in[10];
    const float* outb = (const float*)d_in[11];
    const float* embW = (const float*)d_in[12];
    const float* embb = (const float*)d_in[13];
    const float* mW1  = (const float*)d_in[14];
    const float* mb1  = (const float*)d_in[15];
    const float* mW2  = (const float*)d_in[16];
    const float* mb2  = (const float*)d_in[17];
    const float* cW1  = (const float*)d_in[18];
    const float* cb1  = (const float*)d_in[19];
    const float* cW2  = (const float*)d_in[20];
    const float* cb2  = (const float*)d_in[21];

    float* ws    = (float*)d_ws;
    float* enc_h = ws;                          // 4096*64      = 262144 floats
    float* dec_o = ws + (size_t)BTOT * HDIM;    // 4096*100*16  = 6553600 floats
    float* outp  = (float*)d_out;

    enc_kernel<<<dim3(BTOT / 4), dim3(256), 0, stream>>>(x, eWih, ebih, eWhh, ebhh, enc_h);
    dec_kernel<<<dim3(BTOT / 4), dim3(256), 0, stream>>>(trg, dWih, dbih, dWhh, dbhh,
                                                         outW, outb, embW, embb, enc_h, dec_o);
    heads_kernel<<<dim3((BTOT * SEQLEN) / 256), dim3(256), 0, stream>>>(
        dec_o, mW1, mb1, mW2, mb2, cW1, cb1, cW2, cb2, outp);
}

// Round 2
// 710.797 us; speedup vs baseline: 1.4460x; 1.4460x over previous
//
#include <hip/hip_runtime.h>
#include <cstdint>
#include <cstddef>

// Problem constants (match reference)
#define BTOT    4096
#define SRCLEN  128
#define INDIM   16
#define HDIM    64
#define SEQLEN  100
#define MEANS_N (BTOT * SEQLEN * 4)   // 1638400

// ---------- helpers ----------
__device__ __forceinline__ float dot4(float4 a, float4 b) {
    return fmaf(a.x, b.x, fmaf(a.y, b.y, fmaf(a.z, b.z, a.w * b.w)));
}

// quad butterfly reduce across lanes {4k,4k+1,4k+2,4k+3}; all 4 lanes end with the sum.
template <int CTRL>
__device__ __forceinline__ float dpp_xadd(float v) {
    float o = __int_as_float(__builtin_amdgcn_mov_dpp(__float_as_int(v), CTRL, 0xF, 0xF, true));
    return v + o;
}
__device__ __forceinline__ float quad_sum(float v) {
    v = dpp_xadd<0xB1>(v);  // quad_perm(1,0,3,2)  xor 1
    v = dpp_xadd<0x4E>(v);  // quad_perm(2,3,0,1)  xor 2
    return v;
}

__device__ __forceinline__ float sigmoidf_(float x) { return 1.0f / (1.0f + __expf(-x)); }
__device__ __forceinline__ float tanhf_(float x) {
    float e = __expf(2.0f * x);
    return 1.0f - 2.0f / (e + 1.0f);
}
__device__ __forceinline__ float gelu_exact(float x) {
    return 0.5f * x * (1.0f + erff(x * 0.70710678118654752440f));
}

// ---------- bf16 split helpers (bf16x3 emulated-fp32 MFMA) ----------
typedef __attribute__((ext_vector_type(8))) short s8v;   // 8 bf16 (4 VGPRs) — MFMA A/B frag
typedef __attribute__((ext_vector_type(4))) float f4v;   // 4 fp32 — MFMA C/D frag

__device__ __forceinline__ unsigned short f2bf(float x) {  // RTNE float -> bf16 bits
    unsigned u = __float_as_uint(x);
    unsigned r = (u + 0x7FFFu + ((u >> 16) & 1u)) >> 16;
    return (unsigned short)r;
}
__device__ __forceinline__ float bf2f(unsigned short b) {
    return __uint_as_float(((unsigned)b) << 16);
}
// split 8 fp32 into hi/lo bf16 frags
__device__ __forceinline__ void split2(float4 a, float4 b, s8v& hi, s8v& lo) {
    float v[8] = {a.x, a.y, a.z, a.w, b.x, b.y, b.z, b.w};
    #pragma unroll
    for (int j = 0; j < 8; ++j) {
        unsigned short h = f2bf(v[j]);
        hi[j] = (short)h;
        lo[j] = (short)f2bf(v[j] - bf2f(h));
    }
}
__device__ __forceinline__ void load_bfrag(const float* p, s8v& hi, s8v& lo) {
    float4 a = *(const float4*)p;
    float4 b = *(const float4*)(p + 4);
    split2(a, b, hi, lo);
}

#define MFMA16(a, b, c) __builtin_amdgcn_mfma_f32_16x16x32_bf16((a), (b), (c), 0, 0, 0)

// =====================================================================
// Encoder GRU via MFMA (bf16x3): per WG, M=16 batches, 4 waves; per step
// one [16x80]@[80x192] GEMM as 27 MFMAs/wave.  Grid = 256 WGs (1/CU).
// Wave w owns gate-unit columns u = w*16 + (lane&15) for all 3 gates.
// h kept in LDS pre-split (hi/lo bf16, row pad 72) in MFMA-A order;
// ping-pong buffers -> 1 barrier/step; x_{t+1} prefetched in registers.
// Layouts (m89/m120-verified): A[m=lane&15][k=(lane>>4)*8+j],
// B[n=lane&15][k=(lane>>4)*8+j], D col=lane&15, row=(lane>>4)*4+reg.
// =====================================================================
__global__ __launch_bounds__(256, 1) void enc_mfma_kernel(
    const float* __restrict__ x,
    const float* __restrict__ Wih, const float* __restrict__ bih,
    const float* __restrict__ Whh, const float* __restrict__ bhh,
    float* __restrict__ enc_h)
{
    const int tid  = threadIdx.x;
    const int lane = tid & 63;
    const int w    = tid >> 6;     // wave 0..3
    const int col  = lane & 15;    // A-row m (batch) for A-frags; B/D col (unit) otherwise
    const int q    = lane >> 4;    // k-quad 0..3
    const int u    = w * 16 + col; // gate-local unit index 0..63
    const int b0   = blockIdx.x * 16;

    // h buffers: [buf][batch 16][k 64 (+8 pad -> 2-way-free banks)]
    __shared__ __align__(16) unsigned short hiL[2][16][72];
    __shared__ __align__(16) unsigned short loL[2][16][72];

    for (int i = tid; i < 16 * 72; i += 256) {   // zero buf 0 (h_0 = 0)
        ((unsigned short*)hiL)[i] = 0;
        ((unsigned short*)loL)[i] = 0;
    }

    const s8v z8 = {0, 0, 0, 0, 0, 0, 0, 0};
    const f4v z4 = {0.0f, 0.0f, 0.0f, 0.0f};

    // ---- B fragments (weights), built once into VGPRs ----
    // K layout: k in [0,64) = h (Whh), k in [64,80) = x (Wih), [80,96) = 0.
    s8v brh[3], brl[3], bzh[3], bzl[3], bnhh[2], bnhl[2], bnxh, bnxl;
    load_bfrag(Whh + (size_t)u * 64 + q * 8,              brh[0], brl[0]);
    load_bfrag(Whh + (size_t)u * 64 + 32 + q * 8,         brh[1], brl[1]);
    load_bfrag(Whh + (size_t)(64 + u) * 64 + q * 8,       bzh[0], bzl[0]);
    load_bfrag(Whh + (size_t)(64 + u) * 64 + 32 + q * 8,  bzh[1], bzl[1]);
    load_bfrag(Whh + (size_t)(128 + u) * 64 + q * 8,      bnhh[0], bnhl[0]);
    load_bfrag(Whh + (size_t)(128 + u) * 64 + 32 + q * 8, bnhh[1], bnhl[1]);
    if (q < 2) {   // k-step 2 covers x: rows of Wih, cols q*8..q*8+7 (<16)
        load_bfrag(Wih + (size_t)u * 16 + q * 8,         brh[2], brl[2]);
        load_bfrag(Wih + (size_t)(64 + u) * 16 + q * 8,  bzh[2], bzl[2]);
        load_bfrag(Wih + (size_t)(128 + u) * 16 + q * 8, bnxh, bnxl);
    } else {       // k >= 80 -> zero (must be defined: 0*NaN would poison acc)
        brh[2] = z8; brl[2] = z8; bzh[2] = z8; bzl[2] = z8; bnxh = z8; bnxl = z8;
    }

    const float br   = bih[u] + bhh[u];
    const float bz   = bih[u + 64] + bhh[u + 64];
    const float bnx  = bih[u + 128];   // n-gate: x-part and h-part stay separate (r gates h-part)
    const float bnh  = bhh[u + 128];

    // ---- x frag for t=0 ----
    s8v xh = z8, xl = z8;
    if (q < 2) {
        const float* xp = x + ((size_t)(b0 + col) * SRCLEN + 0) * INDIM + q * 8;
        split2(*(const float4*)xp, *(const float4*)(xp + 4), xh, xl);
    }

    f4v hold = z4;  // h_old for this lane's 4 (batch=(q*4+i), unit=u) slots
    __syncthreads();

    int cur = 0;
    for (int t = 0; t < SRCLEN; ++t) {
        // prefetch x_{t+1} raw (latency hidden across the step)
        float4 nx0, nx1;
        const bool pf = (t + 1 < SRCLEN) && (q < 2);
        if (pf) {
            const float* xp = x + ((size_t)(b0 + col) * SRCLEN + (t + 1)) * INDIM + q * 8;
            nx0 = *(const float4*)xp;
            nx1 = *(const float4*)(xp + 4);
        }

        // A-frags: h of step t (pre-split in LDS)
        const s8v ah0 = *(const s8v*)&hiL[cur][col][q * 8];
        const s8v al0 = *(const s8v*)&loL[cur][col][q * 8];
        const s8v ah1 = *(const s8v*)&hiL[cur][col][32 + q * 8];
        const s8v al1 = *(const s8v*)&loL[cur][col][32 + q * 8];

        f4v accr, accz, accnh, accnx;
        // k-step 0 (h[0:32)) — 3 terms each
        accr  = MFMA16(ah0, brh[0], z4);
        accz  = MFMA16(ah0, bzh[0], z4);
        accnh = MFMA16(ah0, bnhh[0], z4);
        accr  = MFMA16(ah0, brl[0], accr);
        accz  = MFMA16(ah0, bzl[0], accz);
        accnh = MFMA16(ah0, bnhl[0], accnh);
        accr  = MFMA16(al0, brh[0], accr);
        accz  = MFMA16(al0, bzh[0], accz);
        accnh = MFMA16(al0, bnhh[0], accnh);
        // k-step 1 (h[32:64))
        accr  = MFMA16(ah1, brh[1], accr);
        accz  = MFMA16(ah1, bzh[1], accz);
        accnh = MFMA16(ah1, bnhh[1], accnh);
        accr  = MFMA16(ah1, brl[1], accr);
        accz  = MFMA16(ah1, bzl[1], accz);
        accnh = MFMA16(ah1, bnhl[1], accnh);
        accr  = MFMA16(al1, brh[1], accr);
        accz  = MFMA16(al1, bzh[1], accz);
        accnh = MFMA16(al1, bnhh[1], accnh);
        // k-step 2 (x, padded) — n-gate x-part goes to its own accumulator
        accr  = MFMA16(xh, brh[2], accr);
        accz  = MFMA16(xh, bzh[2], accz);
        accnx = MFMA16(xh, bnxh, z4);
        accr  = MFMA16(xh, brl[2], accr);
        accz  = MFMA16(xh, bzl[2], accz);
        accnx = MFMA16(xh, bnxl, accnx);
        accr  = MFMA16(xl, brh[2], accr);
        accz  = MFMA16(xl, bzh[2], accz);
        accnx = MFMA16(xl, bnxh, accnx);

        // pointwise: lane owns (batch = q*4+i, unit = u)
        const int nxt = cur ^ 1;
        #pragma unroll
        for (int i = 0; i < 4; ++i) {
            float r  = sigmoidf_(accr[i] + br);
            float zz = sigmoidf_(accz[i] + bz);
            float n  = tanhf_(accnx[i] + bnx + r * (accnh[i] + bnh));
            float h  = (1.0f - zz) * n + zz * hold[i];
            hold[i] = h;
            unsigned short hh = f2bf(h);
            hiL[nxt][q * 4 + i][u] = hh;
            loL[nxt][q * 4 + i][u] = f2bf(h - bf2f(hh));
        }
        __syncthreads();

        if (t + 1 < SRCLEN) {
            if (q < 2) split2(nx0, nx1, xh, xl);
            // q>=2: xh/xl stay zero
        }
        cur ^= 1;
    }

    #pragma unroll
    for (int i = 0; i < 4; ++i)
        enc_h[(size_t)(b0 + q * 4 + i) * HDIM + u] = hold[i];
}

// =====================================================================
// Decoder GRU: 100 autoregressive steps.  (unchanged from R1 — VALU)
// =====================================================================
__global__ __launch_bounds__(256, 3) void dec_kernel(
    const float* __restrict__ trg,
    const float* __restrict__ Wih, const float* __restrict__ bih,
    const float* __restrict__ Whh, const float* __restrict__ bhh,
    const float* __restrict__ outW, const float* __restrict__ outb,
    const float* __restrict__ embW, const float* __restrict__ embb,
    const float* __restrict__ enc_h,
    float* __restrict__ dec_o)
{
    const int tid = threadIdx.x;
    const int kq  = tid & 3;
    const int u   = tid >> 2;      // 0..63
    const int w   = tid >> 6;      // wave id 0..3 (handles batch b=w in phase3)
    const int ul  = u & 15;        // out-projection row 0..15
    const int b0  = blockIdx.x * 4;

    __shared__ __align__(16) float h_lds[4][HDIM];
    __shared__ __align__(16) float o_lds[4][INDIM];

    { int bb = tid >> 6, uu = tid & 63;
      h_lds[bb][uu] = enc_h[(size_t)(b0 + bb) * HDIM + uu]; }
    if (tid < 64) {  // init_in = trg @ embW^T + embb
        int bb = tid >> 4, ii = tid & 15;
        float s = embb[ii];
        #pragma unroll
        for (int q = 0; q < 4; ++q)
            s = fmaf(embW[ii * 4 + q], trg[(size_t)(b0 + bb) * 4 + q], s);
        o_lds[bb][ii] = s;
    }

    float4 wr[4], wz[4], wn[4];
    #pragma unroll
    for (int c = 0; c < 4; ++c) {
        wr[c] = *(const float4*)(Whh + (size_t)(u)        * HDIM + 16 * kq + 4 * c);
        wz[c] = *(const float4*)(Whh + (size_t)(u + 64)   * HDIM + 16 * kq + 4 * c);
        wn[c] = *(const float4*)(Whh + (size_t)(u + 128)  * HDIM + 16 * kq + 4 * c);
    }
    const float4 gr = *(const float4*)(Wih + (size_t)(u)       * INDIM + 4 * kq);
    const float4 gz = *(const float4*)(Wih + (size_t)(u + 64)  * INDIM + 4 * kq);
    const float4 gn = *(const float4*)(Wih + (size_t)(u + 128) * INDIM + 4 * kq);
    const float br   = bih[u]       + bhh[u];
    const float bz   = bih[u + 64]  + bhh[u + 64];
    const float bin_ = bih[u + 128];
    const float bhn  = bhh[u + 128];
    float4 ow[4];
    #pragma unroll
    for (int c = 0; c < 4; ++c)
        ow[c] = *(const float4*)(outW + (size_t)ul * HDIM + 16 * kq + 4 * c);
    const float ob = outb[ul];

    __syncthreads();

    for (int t = 0; t < SEQLEN; ++t) {
        // phase1: gate dot products (reads h_lds old, o_lds old)
        float ar[4], az[4], anh[4], anx[4], hold[4];
        #pragma unroll
        for (int b = 0; b < 4; ++b) {
            const float4* hp = (const float4*)(&h_lds[b][16 * kq]);
            const float4 h0 = hp[0], h1 = hp[1], h2 = hp[2], h3 = hp[3];
            const float4 ov = *(const float4*)(&o_lds[b][4 * kq]);
            float r_  = dot4(wr[0], h0) + dot4(wr[1], h1) + dot4(wr[2], h2) + dot4(wr[3], h3) + dot4(gr, ov);
            float z_  = dot4(wz[0], h0) + dot4(wz[1], h1) + dot4(wz[2], h2) + dot4(wz[3], h3) + dot4(gz, ov);
            float nh_ = dot4(wn[0], h0) + dot4(wn[1], h1) + dot4(wn[2], h2) + dot4(wn[3], h3);
            float nx_ = dot4(gn, ov);
            ar[b]  = quad_sum(r_);
            az[b]  = quad_sum(z_);
            anh[b] = quad_sum(nh_);
            anx[b] = quad_sum(nx_);
            hold[b] = h_lds[b][u];
        }
        __syncthreads();
        // phase2: pointwise GRU update, write h_new
        #pragma unroll
        for (int b = 0; b < 4; ++b) {
            float r = sigmoidf_(ar[b] + br);
            float z = sigmoidf_(az[b] + bz);
            float n = tanhf_(anx[b] + bin_ + r * (anh[b] + bhn));
            float hnew = (1.0f - z) * n + z * hold[b];
            if (kq == 0) h_lds[b][u] = hnew;
        }
        __syncthreads();
        // phase3: o = h_new @ outW^T + outb ; wave w computes batch b=w
        {
            const float4* hp = (const float4*)(&h_lds[w][16 * kq]);
            float acc = dot4(ow[0], hp[0]) + dot4(ow[1], hp[1]) + dot4(ow[2], hp[2]) + dot4(ow[3], hp[3]);
            acc = quad_sum(acc) + ob;
            if (kq == 0) {
                o_lds[w][ul] = acc;
                dec_o[(((size_t)(b0 + w) * SEQLEN) + t) * INDIM + ul] = acc;
            }
        }
        __syncthreads();
    }
}

// =====================================================================
// Heads: 409600 independent rows; one thread per row. (unchanged from R1)
// =====================================================================
__global__ void heads_kernel(
    const float* __restrict__ dec_o,
    const float* __restrict__ mW1, const float* __restrict__ mb1,
    const float* __restrict__ mW2, const float* __restrict__ mb2,
    const float* __restrict__ cW1, const float* __restrict__ cb1,
    const float* __restrict__ cW2, const float* __restrict__ cb2,
    float* __restrict__ out)
{
    const size_t r = (size_t)blockIdx.x * 256 + threadIdx.x;  // 0..409599

    float o16[16];
    {
        const float4* op = (const float4*)(dec_o + r * 16);
        #pragma unroll
        for (int c = 0; c < 4; ++c) {
            float4 v = op[c];
            o16[4 * c + 0] = v.x; o16[4 * c + 1] = v.y;
            o16[4 * c + 2] = v.z; o16[4 * c + 3] = v.w;
        }
    }

    float m[4], cv[10];
    #pragma unroll
    for (int j = 0; j < 4; ++j)  m[j]  = mb2[j];
    #pragma unroll
    for (int j = 0; j < 10; ++j) cv[j] = cb2[j];

    #pragma unroll 8
    for (int hu = 0; hu < 64; ++hu) {
        const float* w1m = mW1 + hu * 16;
        float hm = mb1[hu];
        #pragma unroll
        for (int i = 0; i < 16; ++i) hm = fmaf(w1m[i], o16[i], hm);
        float gm = gelu_exact(hm);
        #pragma unroll
        for (int j = 0; j < 4; ++j) m[j] = fmaf(mW2[j * 64 + hu], gm, m[j]);

        const float* w1c = cW1 + hu * 16;
        float hc = cb1[hu];
        #pragma unroll
        for (int i = 0; i < 16; ++i) hc = fmaf(w1c[i], o16[i], hc);
        float gc = gelu_exact(hc);
        #pragma unroll
        for (int j = 0; j < 10; ++j) cv[j] = fmaf(cW2[j * 64 + hu], gc, cv[j]);
    }

    // clamp means[2],[3] to [-1,1]; [0],[1] pass through
    m[2] = fminf(fmaxf(m[2], -1.0f), 1.0f);
    m[3] = fminf(fmaxf(m[3], -1.0f), 1.0f);

    float* means = out;
    float* covs  = out + MEANS_N;
    #pragma unroll
    for (int j = 0; j < 4; ++j)  means[r * 4 + j]  = m[j];
    #pragma unroll
    for (int j = 0; j < 10; ++j) covs[r * 10 + j]  = cv[j];
}

// =====================================================================
extern "C" void kernel_launch(void* const* d_in, const int* in_sizes, int n_in,
                              void* d_out, int out_size, void* d_ws, size_t ws_size,
                              hipStream_t stream)
{
    const float* x    = (const float*)d_in[0];
    const float* trg  = (const float*)d_in[1];
    const float* eWih = (const float*)d_in[2];
    const float* ebih = (const float*)d_in[3];
    const float* eWhh = (const float*)d_in[4];
    const float* ebhh = (const float*)d_in[5];
    const float* dWih = (const float*)d_in[6];
    const float* dbih = (const float*)d_in[7];
    const float* dWhh = (const float*)d_in[8];
    const float* dbhh = (const float*)d_in[9];
    const float* outW = (const float*)d_in[10];
    const float* outb = (const float*)d_in[11];
    const float* embW = (const float*)d_in[12];
    const float* embb = (const float*)d_in[13];
    const float* mW1  = (const float*)d_in[14];
    const float* mb1  = (const float*)d_in[15];
    const float* mW2  = (const float*)d_in[16];
    const float* mb2  = (const float*)d_in[17];
    const float* cW1  = (const float*)d_in[18];
    const float* cb1  = (const float*)d_in[19];
    const float* cW2  = (const float*)d_in[20];
    const float* cb2  = (const float*)d_in[21];

    float* ws    = (float*)d_ws;
    float* enc_h = ws;                          // 4096*64      = 262144 floats
    float* dec_o = ws + (size_t)BTOT * HDIM;    // 4096*100*16  = 6553600 floats
    float* outp  = (float*)d_out;

    enc_mfma_kernel<<<dim3(BTOT / 16), dim3(256), 0, stream>>>(x, eWih, ebih, eWhh, ebhh, enc_h);
    dec_kernel<<<dim3(BTOT / 4), dim3(256), 0, stream>>>(trg, dWih, dbih, dWhh, dbhh,
                                                         outW, outb, embW, embb, enc_h, dec_o);
    heads_kernel<<<dim3((BTOT * SEQLEN) / 256), dim3(256), 0, stream>>>(
        dec_o, mW1, mb1, mW2, mb2, cW1, cb1, cW2, cb2, outp);
}

// Round 3
// 435.861 us; speedup vs baseline: 2.3580x; 1.6308x over previous
//
#include <hip/hip_runtime.h>
#include <cstdint>
#include <cstddef>

// Problem constants (match reference)
#define BTOT    4096
#define SRCLEN  128
#define INDIM   16
#define HDIM    64
#define SEQLEN  100
#define MEANS_N (BTOT * SEQLEN * 4)   // 1638400

// ---------- helpers ----------
__device__ __forceinline__ float sigmoidf_(float x) { return 1.0f / (1.0f + __expf(-x)); }
__device__ __forceinline__ float tanhf_(float x) {
    float e = __expf(2.0f * x);
    return 1.0f - 2.0f / (e + 1.0f);
}
__device__ __forceinline__ float gelu_exact(float x) {
    return 0.5f * x * (1.0f + erff(x * 0.70710678118654752440f));
}

// ---------- bf16 split helpers (bf16x3 emulated-fp32 MFMA) ----------
typedef __attribute__((ext_vector_type(8))) short s8v;   // 8 bf16 (4 VGPRs) — MFMA A/B frag
typedef __attribute__((ext_vector_type(4))) float f4v;   // 4 fp32 — MFMA C/D frag

__device__ __forceinline__ unsigned short f2bf(float x) {  // RTNE float -> bf16 bits
    unsigned u = __float_as_uint(x);
    unsigned r = (u + 0x7FFFu + ((u >> 16) & 1u)) >> 16;
    return (unsigned short)r;
}
__device__ __forceinline__ float bf2f(unsigned short b) {
    return __uint_as_float(((unsigned)b) << 16);
}
// split 8 fp32 into hi/lo bf16 frags
__device__ __forceinline__ void split2(float4 a, float4 b, s8v& hi, s8v& lo) {
    float v[8] = {a.x, a.y, a.z, a.w, b.x, b.y, b.z, b.w};
    #pragma unroll
    for (int j = 0; j < 8; ++j) {
        unsigned short h = f2bf(v[j]);
        hi[j] = (short)h;
        lo[j] = (short)f2bf(v[j] - bf2f(h));
    }
}
__device__ __forceinline__ void split8(const float* v, s8v& hi, s8v& lo) {
    #pragma unroll
    for (int j = 0; j < 8; ++j) {
        unsigned short h = f2bf(v[j]);
        hi[j] = (short)h;
        lo[j] = (short)f2bf(v[j] - bf2f(h));
    }
}
__device__ __forceinline__ void load_bfrag(const float* p, s8v& hi, s8v& lo) {
    float4 a = *(const float4*)p;
    float4 b = *(const float4*)(p + 4);
    split2(a, b, hi, lo);
}

#define MFMA16(a, b, c) __builtin_amdgcn_mfma_f32_16x16x32_bf16((a), (b), (c), 0, 0, 0)

// =====================================================================
// Encoder GRU via MFMA (bf16x3) — UNCHANGED from R2 (known-good, ~221 us).
// =====================================================================
__global__ __launch_bounds__(256, 1) void enc_mfma_kernel(
    const float* __restrict__ x,
    const float* __restrict__ Wih, const float* __restrict__ bih,
    const float* __restrict__ Whh, const float* __restrict__ bhh,
    float* __restrict__ enc_h)
{
    const int tid  = threadIdx.x;
    const int lane = tid & 63;
    const int w    = tid >> 6;     // wave 0..3
    const int col  = lane & 15;
    const int q    = lane >> 4;
    const int u    = w * 16 + col;
    const int b0   = blockIdx.x * 16;

    __shared__ __align__(16) unsigned short hiL[2][16][72];
    __shared__ __align__(16) unsigned short loL[2][16][72];

    for (int i = tid; i < 16 * 72; i += 256) {
        ((unsigned short*)hiL)[i] = 0;
        ((unsigned short*)loL)[i] = 0;
    }

    const s8v z8 = {0, 0, 0, 0, 0, 0, 0, 0};
    const f4v z4 = {0.0f, 0.0f, 0.0f, 0.0f};

    s8v brh[3], brl[3], bzh[3], bzl[3], bnhh[2], bnhl[2], bnxh, bnxl;
    load_bfrag(Whh + (size_t)u * 64 + q * 8,              brh[0], brl[0]);
    load_bfrag(Whh + (size_t)u * 64 + 32 + q * 8,         brh[1], brl[1]);
    load_bfrag(Whh + (size_t)(64 + u) * 64 + q * 8,       bzh[0], bzl[0]);
    load_bfrag(Whh + (size_t)(64 + u) * 64 + 32 + q * 8,  bzh[1], bzl[1]);
    load_bfrag(Whh + (size_t)(128 + u) * 64 + q * 8,      bnhh[0], bnhl[0]);
    load_bfrag(Whh + (size_t)(128 + u) * 64 + 32 + q * 8, bnhh[1], bnhl[1]);
    if (q < 2) {
        load_bfrag(Wih + (size_t)u * 16 + q * 8,         brh[2], brl[2]);
        load_bfrag(Wih + (size_t)(64 + u) * 16 + q * 8,  bzh[2], bzl[2]);
        load_bfrag(Wih + (size_t)(128 + u) * 16 + q * 8, bnxh, bnxl);
    } else {
        brh[2] = z8; brl[2] = z8; bzh[2] = z8; bzl[2] = z8; bnxh = z8; bnxl = z8;
    }

    const float br   = bih[u] + bhh[u];
    const float bz   = bih[u + 64] + bhh[u + 64];
    const float bnx  = bih[u + 128];
    const float bnh  = bhh[u + 128];

    s8v xh = z8, xl = z8;
    if (q < 2) {
        const float* xp = x + ((size_t)(b0 + col) * SRCLEN + 0) * INDIM + q * 8;
        split2(*(const float4*)xp, *(const float4*)(xp + 4), xh, xl);
    }

    f4v hold = z4;
    __syncthreads();

    int cur = 0;
    for (int t = 0; t < SRCLEN; ++t) {
        float4 nx0, nx1;
        const bool pf = (t + 1 < SRCLEN) && (q < 2);
        if (pf) {
            const float* xp = x + ((size_t)(b0 + col) * SRCLEN + (t + 1)) * INDIM + q * 8;
            nx0 = *(const float4*)xp;
            nx1 = *(const float4*)(xp + 4);
        }

        const s8v ah0 = *(const s8v*)&hiL[cur][col][q * 8];
        const s8v al0 = *(const s8v*)&loL[cur][col][q * 8];
        const s8v ah1 = *(const s8v*)&hiL[cur][col][32 + q * 8];
        const s8v al1 = *(const s8v*)&loL[cur][col][32 + q * 8];

        f4v accr, accz, accnh, accnx;
        accr  = MFMA16(ah0, brh[0], z4);
        accz  = MFMA16(ah0, bzh[0], z4);
        accnh = MFMA16(ah0, bnhh[0], z4);
        accr  = MFMA16(ah0, brl[0], accr);
        accz  = MFMA16(ah0, bzl[0], accz);
        accnh = MFMA16(ah0, bnhl[0], accnh);
        accr  = MFMA16(al0, brh[0], accr);
        accz  = MFMA16(al0, bzh[0], accz);
        accnh = MFMA16(al0, bnhh[0], accnh);
        accr  = MFMA16(ah1, brh[1], accr);
        accz  = MFMA16(ah1, bzh[1], accz);
        accnh = MFMA16(ah1, bnhh[1], accnh);
        accr  = MFMA16(ah1, brl[1], accr);
        accz  = MFMA16(ah1, bzl[1], accz);
        accnh = MFMA16(ah1, bnhl[1], accnh);
        accr  = MFMA16(al1, brh[1], accr);
        accz  = MFMA16(al1, bzh[1], accz);
        accnh = MFMA16(al1, bnhh[1], accnh);
        accr  = MFMA16(xh, brh[2], accr);
        accz  = MFMA16(xh, bzh[2], accz);
        accnx = MFMA16(xh, bnxh, z4);
        accr  = MFMA16(xh, brl[2], accr);
        accz  = MFMA16(xh, bzl[2], accz);
        accnx = MFMA16(xh, bnxl, accnx);
        accr  = MFMA16(xl, brh[2], accr);
        accz  = MFMA16(xl, bzh[2], accz);
        accnx = MFMA16(xl, bnxh, accnx);

        const int nxt = cur ^ 1;
        #pragma unroll
        for (int i = 0; i < 4; ++i) {
            float r  = sigmoidf_(accr[i] + br);
            float zz = sigmoidf_(accz[i] + bz);
            float n  = tanhf_(accnx[i] + bnx + r * (accnh[i] + bnh));
            float h  = (1.0f - zz) * n + zz * hold[i];
            hold[i] = h;
            unsigned short hh = f2bf(h);
            hiL[nxt][q * 4 + i][u] = hh;
            loL[nxt][q * 4 + i][u] = f2bf(h - bf2f(hh));
        }
        __syncthreads();

        if (t + 1 < SRCLEN) {
            if (q < 2) split2(nx0, nx1, xh, xl);
        }
        cur ^= 1;
    }

    #pragma unroll
    for (int i = 0; i < 4; ++i)
        enc_h[(size_t)(b0 + q * 4 + i) * HDIM + u] = hold[i];
}

// =====================================================================
// Decoder GRU via MFMA with out-projection FOLDED INTO the recurrence.
// For t>=1: inp_t = h_t@outW^T + outb (no nonlinearity), so
//   gi_t = h_t @ Wcomb^T + (bih + outb@Wih^T),  Wcomb = Wih @ outW [192x64].
// r,z gates merge Wcomb into Whh (one matrix); i_n and h_n stay separate
// (n = tanh(i_n + r*h_n)).  Per step per wave: 4 tiles x 6 MFMAs = 24.
// o_t (heads input only) computed by wave 0 from the same A-frags at the
// top of step t+1 (+6 MFMAs) and stored straight to global (D-layout).
// Step 0 (inp_0 = embedding) special-cased: gi0 via VALU + Whh-only frags.
// =====================================================================
__global__ __launch_bounds__(256, 1) void dec_mfma_kernel(
    const float* __restrict__ trg,
    const float* __restrict__ Wih, const float* __restrict__ bih,
    const float* __restrict__ Whh, const float* __restrict__ bhh,
    const float* __restrict__ outW, const float* __restrict__ outb,
    const float* __restrict__ embW, const float* __restrict__ embb,
    const float* __restrict__ enc_h,
    float* __restrict__ dec_o)
{
    const int tid  = threadIdx.x;
    const int lane = tid & 63;
    const int w    = tid >> 6;
    const int col  = lane & 15;
    const int q    = lane >> 4;
    const int u    = w * 16 + col;
    const int b0   = blockIdx.x * 16;

    __shared__ __align__(16) unsigned short hiL[2][16][72];
    __shared__ __align__(16) unsigned short loL[2][16][72];
    __shared__ float outW_l[16][64];   // staged outW (for Wcomb + o-frags)
    __shared__ float init_l[16][16];   // init_in per batch

    // ---- stage LDS: outW, init_in, h0-split into buf0 ----
    for (int i = tid; i < 16 * 64; i += 256) outW_l[i >> 6][i & 63] = outW[i];
    {
        int b = tid >> 4, jj = tid & 15;
        float s = embb[jj];
        #pragma unroll
        for (int s4 = 0; s4 < 4; ++s4)
            s = fmaf(embW[jj * 4 + s4], trg[(size_t)(b0 + b) * 4 + s4], s);
        init_l[b][jj] = s;
    }
    {
        int idx = tid * 4;                  // 1024 floats of h0 for this WG
        int bb = idx >> 6, uu = idx & 63;
        float4 v = *(const float4*)(enc_h + (size_t)(b0 + bb) * HDIM + uu);
        float vv[4] = {v.x, v.y, v.z, v.w};
        #pragma unroll
        for (int j = 0; j < 4; ++j) {
            unsigned short hh = f2bf(vv[j]);
            hiL[0][bb][uu + j] = hh;
            loL[0][bb][uu + j] = f2bf(vv[j] - bf2f(hh));
        }
    }
    // h_old for this lane's 4 (batch, unit=u) slots
    f4v hold;
    #pragma unroll
    for (int i = 0; i < 4; ++i)
        hold[i] = enc_h[(size_t)(b0 + q * 4 + i) * HDIM + u];

    __syncthreads();

    const f4v z4 = {0.0f, 0.0f, 0.0f, 0.0f};

    // ---- fp32 weight rows for this lane's k-slice (k = c*32 + q*8 + jj) ----
    float wh_r[16], wh_z[16], wh_n[16];
    #pragma unroll
    for (int c = 0; c < 2; ++c)
        #pragma unroll
        for (int jj = 0; jj < 8; ++jj) {
            int k = c * 32 + q * 8 + jj;
            wh_r[c * 8 + jj] = Whh[(size_t)u * 64 + k];
            wh_z[c * 8 + jj] = Whh[(size_t)(64 + u) * 64 + k];
            wh_n[c * 8 + jj] = Whh[(size_t)(128 + u) * 64 + k];
        }
    float wi_r[16], wi_z[16], wi_n[16];
    #pragma unroll
    for (int j = 0; j < 16; ++j) {
        wi_r[j] = Wih[(size_t)u * 16 + j];
        wi_z[j] = Wih[(size_t)(64 + u) * 16 + j];
        wi_n[j] = Wih[(size_t)(128 + u) * 16 + j];
    }

    // ---- Wcomb = Wih @ outW; merge into r/z; i_n separate ----
    float m_r[16], m_z[16], c_in[16];
    #pragma unroll
    for (int c = 0; c < 2; ++c)
        #pragma unroll
        for (int jj = 0; jj < 8; ++jj) {
            int k = c * 32 + q * 8 + jj;
            float sr = 0.0f, sz = 0.0f, sn = 0.0f;
            #pragma unroll
            for (int j = 0; j < 16; ++j) {
                float ow = outW_l[j][k];
                sr = fmaf(wi_r[j], ow, sr);
                sz = fmaf(wi_z[j], ow, sz);
                sn = fmaf(wi_n[j], ow, sn);
            }
            m_r[c * 8 + jj]  = wh_r[c * 8 + jj] + sr;
            m_z[c * 8 + jj]  = wh_z[c * 8 + jj] + sz;
            c_in[c * 8 + jj] = sn;
        }

    // ---- B-frags (steady state) ----
    s8v mrh[2], mrl[2], mzh[2], mzl[2], cinh[2], cinl[2], hnh[2], hnl[2];
    split8(m_r,      mrh[0],  mrl[0]);  split8(m_r + 8,  mrh[1],  mrl[1]);
    split8(m_z,      mzh[0],  mzl[0]);  split8(m_z + 8,  mzh[1],  mzl[1]);
    split8(c_in,     cinh[0], cinl[0]); split8(c_in + 8, cinh[1], cinl[1]);
    split8(wh_n,     hnh[0],  hnl[0]);  split8(wh_n + 8, hnh[1],  hnl[1]);
    // step-0 Whh-only r/z frags
    s8v r0h[2], r0l[2], z0h[2], z0l[2];
    split8(wh_r, r0h[0], r0l[0]); split8(wh_r + 8, r0h[1], r0l[1]);
    split8(wh_z, z0h[0], z0l[0]); split8(wh_z + 8, z0h[1], z0l[1]);
    // o-projection frags: B[n=col][k] = outW[col][k]
    s8v owh[2], owl[2];
    {
        float ov[16];
        #pragma unroll
        for (int c = 0; c < 2; ++c)
            #pragma unroll
            for (int jj = 0; jj < 8; ++jj)
                ov[c * 8 + jj] = outW_l[col][c * 32 + q * 8 + jj];
        split8(ov, owh[0], owl[0]); split8(ov + 8, owh[1], owl[1]);
    }

    // ---- folded biases ----
    float b_r = bhh[u] + bih[u];
    float b_z = bhh[u + 64] + bih[u + 64];
    float b_in = bih[u + 128];
    const float b_hn = bhh[u + 128];
    #pragma unroll
    for (int j = 0; j < 16; ++j) {
        float obj = outb[j];
        b_r  = fmaf(obj, wi_r[j], b_r);
        b_z  = fmaf(obj, wi_z[j], b_z);
        b_in = fmaf(obj, wi_n[j], b_in);
    }
    const float ob = outb[col];

    // ---- gi0 from init_in (per lane, 4 batches) ----
    float g_r[4], g_z[4], g_n[4];
    #pragma unroll
    for (int i = 0; i < 4; ++i) {
        float sr = bih[u] + bhh[u];
        float sz = bih[u + 64] + bhh[u + 64];
        float sn = bih[u + 128];
        #pragma unroll
        for (int j = 0; j < 16; ++j) {
            float iv = init_l[q * 4 + i][j];
            sr = fmaf(wi_r[j], iv, sr);
            sz = fmaf(wi_z[j], iv, sz);
            sn = fmaf(wi_n[j], iv, sn);
        }
        g_r[i] = sr; g_z[i] = sz; g_n[i] = sn;
    }

    // ---- step 0: h1 = GRU(h0, init_in) ----
    {
        const s8v ah0 = *(const s8v*)&hiL[0][col][q * 8];
        const s8v al0 = *(const s8v*)&loL[0][col][q * 8];
        const s8v ah1 = *(const s8v*)&hiL[0][col][32 + q * 8];
        const s8v al1 = *(const s8v*)&loL[0][col][32 + q * 8];
        f4v ar, az, ahn;
        ar  = MFMA16(ah0, r0h[0], z4);
        az  = MFMA16(ah0, z0h[0], z4);
        ahn = MFMA16(ah0, hnh[0], z4);
        ar  = MFMA16(ah0, r0l[0], ar);
        az  = MFMA16(ah0, z0l[0], az);
        ahn = MFMA16(ah0, hnl[0], ahn);
        ar  = MFMA16(al0, r0h[0], ar);
        az  = MFMA16(al0, z0h[0], az);
        ahn = MFMA16(al0, hnh[0], ahn);
        ar  = MFMA16(ah1, r0h[1], ar);
        az  = MFMA16(ah1, z0h[1], az);
        ahn = MFMA16(ah1, hnh[1], ahn);
        ar  = MFMA16(ah1, r0l[1], ar);
        az  = MFMA16(ah1, z0l[1], az);
        ahn = MFMA16(ah1, hnl[1], ahn);
        ar  = MFMA16(al1, r0h[1], ar);
        az  = MFMA16(al1, z0h[1], az);
        ahn = MFMA16(al1, hnh[1], ahn);
        #pragma unroll
        for (int i = 0; i < 4; ++i) {
            float r  = sigmoidf_(ar[i] + g_r[i]);
            float zz = sigmoidf_(az[i] + g_z[i]);
            float n  = tanhf_(g_n[i] + r * (ahn[i] + b_hn));
            float h  = (1.0f - zz) * n + zz * hold[i];
            hold[i] = h;
            unsigned short hh = f2bf(h);
            hiL[1][q * 4 + i][u] = hh;
            loL[1][q * 4 + i][u] = f2bf(h - bf2f(hh));
        }
        __syncthreads();
    }

    // ---- steps 1..99 (merged weights); o_{t-1} by wave 0 ----
    for (int t = 1; t < SEQLEN; ++t) {
        const int cur = t & 1;
        const s8v ah0 = *(const s8v*)&hiL[cur][col][q * 8];
        const s8v al0 = *(const s8v*)&loL[cur][col][q * 8];
        const s8v ah1 = *(const s8v*)&hiL[cur][col][32 + q * 8];
        const s8v al1 = *(const s8v*)&loL[cur][col][32 + q * 8];

        if (w == 0) {  // o_{t-1} = h_t @ outW^T + outb
            f4v oa;
            oa = MFMA16(ah0, owh[0], z4);
            oa = MFMA16(ah0, owl[0], oa);
            oa = MFMA16(al0, owh[0], oa);
            oa = MFMA16(ah1, owh[1], oa);
            oa = MFMA16(ah1, owl[1], oa);
            oa = MFMA16(al1, owh[1], oa);
            #pragma unroll
            for (int i = 0; i < 4; ++i)
                dec_o[(((size_t)(b0 + q * 4 + i) * SEQLEN) + (t - 1)) * INDIM + col] = oa[i] + ob;
        }

        f4v ar, az, ain, ahn;
        ar  = MFMA16(ah0, mrh[0], z4);
        az  = MFMA16(ah0, mzh[0], z4);
        ain = MFMA16(ah0, cinh[0], z4);
        ahn = MFMA16(ah0, hnh[0], z4);
        ar  = MFMA16(ah0, mrl[0], ar);
        az  = MFMA16(ah0, mzl[0], az);
        ain = MFMA16(ah0, cinl[0], ain);
        ahn = MFMA16(ah0, hnl[0], ahn);
        ar  = MFMA16(al0, mrh[0], ar);
        az  = MFMA16(al0, mzh[0], az);
        ain = MFMA16(al0, cinh[0], ain);
        ahn = MFMA16(al0, hnh[0], ahn);
        ar  = MFMA16(ah1, mrh[1], ar);
        az  = MFMA16(ah1, mzh[1], az);
        ain = MFMA16(ah1, cinh[1], ain);
        ahn = MFMA16(ah1, hnh[1], ahn);
        ar  = MFMA16(ah1, mrl[1], ar);
        az  = MFMA16(ah1, mzl[1], az);
        ain = MFMA16(ah1, cinl[1], ain);
        ahn = MFMA16(ah1, hnl[1], ahn);
        ar  = MFMA16(al1, mrh[1], ar);
        az  = MFMA16(al1, mzh[1], az);
        ain = MFMA16(al1, cinh[1], ain);
        ahn = MFMA16(al1, hnh[1], ahn);

        const int nxt = cur ^ 1;
        #pragma unroll
        for (int i = 0; i < 4; ++i) {
            float r  = sigmoidf_(ar[i] + b_r);
            float zz = sigmoidf_(az[i] + b_z);
            float n  = tanhf_(ain[i] + b_in + r * (ahn[i] + b_hn));
            float h  = (1.0f - zz) * n + zz * hold[i];
            hold[i] = h;
            unsigned short hh = f2bf(h);
            hiL[nxt][q * 4 + i][u] = hh;
            loL[nxt][q * 4 + i][u] = f2bf(h - bf2f(hh));
        }
        __syncthreads();
    }

    // ---- epilogue: o_99 = h_100 @ outW^T + outb (buf 0) ----
    if (w == 0) {
        const s8v ah0 = *(const s8v*)&hiL[0][col][q * 8];
        const s8v al0 = *(const s8v*)&loL[0][col][q * 8];
        const s8v ah1 = *(const s8v*)&hiL[0][col][32 + q * 8];
        const s8v al1 = *(const s8v*)&loL[0][col][32 + q * 8];
        f4v oa;
        oa = MFMA16(ah0, owh[0], z4);
        oa = MFMA16(ah0, owl[0], oa);
        oa = MFMA16(al0, owh[0], oa);
        oa = MFMA16(ah1, owh[1], oa);
        oa = MFMA16(ah1, owl[1], oa);
        oa = MFMA16(al1, owh[1], oa);
        #pragma unroll
        for (int i = 0; i < 4; ++i)
            dec_o[(((size_t)(b0 + q * 4 + i) * SEQLEN) + (SEQLEN - 1)) * INDIM + col] = oa[i] + ob;
    }
}

// =====================================================================
// Heads: 409600 independent rows; one thread per row. (unchanged)
// =====================================================================
__global__ void heads_kernel(
    const float* __restrict__ dec_o,
    const float* __restrict__ mW1, const float* __restrict__ mb1,
    const float* __restrict__ mW2, const float* __restrict__ mb2,
    const float* __restrict__ cW1, const float* __restrict__ cb1,
    const float* __restrict__ cW2, const float* __restrict__ cb2,
    float* __restrict__ out)
{
    const size_t r = (size_t)blockIdx.x * 256 + threadIdx.x;  // 0..409599

    float o16[16];
    {
        const float4* op = (const float4*)(dec_o + r * 16);
        #pragma unroll
        for (int c = 0; c < 4; ++c) {
            float4 v = op[c];
            o16[4 * c + 0] = v.x; o16[4 * c + 1] = v.y;
            o16[4 * c + 2] = v.z; o16[4 * c + 3] = v.w;
        }
    }

    float m[4], cv[10];
    #pragma unroll
    for (int j = 0; j < 4; ++j)  m[j]  = mb2[j];
    #pragma unroll
    for (int j = 0; j < 10; ++j) cv[j] = cb2[j];

    #pragma unroll 8
    for (int hu = 0; hu < 64; ++hu) {
        const float* w1m = mW1 + hu * 16;
        float hm = mb1[hu];
        #pragma unroll
        for (int i = 0; i < 16; ++i) hm = fmaf(w1m[i], o16[i], hm);
        float gm = gelu_exact(hm);
        #pragma unroll
        for (int j = 0; j < 4; ++j) m[j] = fmaf(mW2[j * 64 + hu], gm, m[j]);

        const float* w1c = cW1 + hu * 16;
        float hc = cb1[hu];
        #pragma unroll
        for (int i = 0; i < 16; ++i) hc = fmaf(w1c[i], o16[i], hc);
        float gc = gelu_exact(hc);
        #pragma unroll
        for (int j = 0; j < 10; ++j) cv[j] = fmaf(cW2[j * 64 + hu], gc, cv[j]);
    }

    m[2] = fminf(fmaxf(m[2], -1.0f), 1.0f);
    m[3] = fminf(fmaxf(m[3], -1.0f), 1.0f);

    float* means = out;
    float* covs  = out + MEANS_N;
    #pragma unroll
    for (int j = 0; j < 4; ++j)  means[r * 4 + j]  = m[j];
    #pragma unroll
    for (int j = 0; j < 10; ++j) covs[r * 10 + j]  = cv[j];
}

// =====================================================================
extern "C" void kernel_launch(void* const* d_in, const int* in_sizes, int n_in,
                              void* d_out, int out_size, void* d_ws, size_t ws_size,
                              hipStream_t stream)
{
    const float* x    = (const float*)d_in[0];
    const float* trg  = (const float*)d_in[1];
    const float* eWih = (const float*)d_in[2];
    const float* ebih = (const float*)d_in[3];
    const float* eWhh = (const float*)d_in[4];
    const float* ebhh = (const float*)d_in[5];
    const float* dWih = (const float*)d_in[6];
    const float* dbih = (const float*)d_in[7];
    const float* dWhh = (const float*)d_in[8];
    const float* dbhh = (const float*)d_in[9];
    const float* outW = (const float*)d_in[10];
    const float* outb = (const float*)d_in[11];
    const float* embW = (const float*)d_in[12];
    const float* embb = (const float*)d_in[13];
    const float* mW1  = (const float*)d_in[14];
    const float* mb1  = (const float*)d_in[15];
    const float* mW2  = (const float*)d_in[16];
    const float* mb2  = (const float*)d_in[17];
    const float* cW1  = (const float*)d_in[18];
    const float* cb1  = (const float*)d_in[19];
    const float* cW2  = (const float*)d_in[20];
    const float* cb2  = (const float*)d_in[21];

    float* ws    = (float*)d_ws;
    float* enc_h = ws;                          // 4096*64      = 262144 floats
    float* dec_o = ws + (size_t)BTOT * HDIM;    // 4096*100*16  = 6553600 floats
    float* outp  = (float*)d_out;

    enc_mfma_kernel<<<dim3(BTOT / 16), dim3(256), 0, stream>>>(x, eWih, ebih, eWhh, ebhh, enc_h);
    dec_mfma_kernel<<<dim3(BTOT / 16), dim3(256), 0, stream>>>(trg, dWih, dbih, dWhh, dbhh,
                                                               outW, outb, embW, embb, enc_h, dec_o);
    heads_kernel<<<dim3((BTOT * SEQLEN) / 256), dim3(256), 0, stream>>>(
        dec_o, mW1, mb1, mW2, mb2, cW1, cb1, cW2, cb2, outp);
}